// Round 16
// baseline (5867.039 us; speedup 1.0000x reference)
//
#include <hip/hip_runtime.h>
#include <hip/hip_bf16.h>

// CharRNN: embed -> 4x (LayerNorm-LSTM over T=128) -> projection to vocab.
// Round 15: 2-layer pipelining. Each cooperative launch runs a layer PAIR:
// blocks 0-127 = layer A, 128-255 = layer B (one step behind, consuming
// x(B)[t] = h(A)[t] via barA2 polls). zx eliminated: kh0 waves compute the
// x-part (K 0..1023), kh1 the h-part (K 1024..2047), merged via LDS pred.
// W-hi (32 cols x K=2048, 128KB) pinned in LDS; W-lo streamed from L2 in a
// slice-contiguous lane-read layout (coalesced 1KB/wave-instr). Critical
// path: 2 x ~129 steps instead of 4 x 128. Projection = round-10 standalone.

typedef __bf16 bf16x8 __attribute__((ext_vector_type(8)));
typedef __bf16 bf16x4 __attribute__((ext_vector_type(4)));
typedef float  f32x4  __attribute__((ext_vector_type(4)));

#define VOCAB 32000
#define BATCH 32
#define SEQ   128
#define RNN   1024
#define NLAY  4
#define GBLK  128
#define AR_STRIDE 16            // dwords between arrival slots (64 B)
#define SLICE_ELEMS 131072      // 32 cols x 2048 k x 2 planes
#define LAYER_ELEMS ((size_t)GBLK * SLICE_ELEMS)

__device__ __forceinline__ float sigm(float x) { return 1.f / (1.f + __expf(-x)); }

// ---- agent-scope relaxed atomics (sc1: coherence-point, bypass stale L2) ----
__device__ __forceinline__ unsigned ald(const unsigned* p) {
    return __hip_atomic_load(p, __ATOMIC_RELAXED, __HIP_MEMORY_SCOPE_AGENT);
}
__device__ __forceinline__ void ast(unsigned* p, unsigned v) {
    __hip_atomic_store(p, v, __ATOMIC_RELAXED, __HIP_MEMORY_SCOPE_AGENT);
}
__device__ __forceinline__ unsigned long long ald64(const unsigned long long* p) {
    return __hip_atomic_load(p, __ATOMIC_RELAXED, __HIP_MEMORY_SCOPE_AGENT);
}
__device__ __forceinline__ void ast64(unsigned long long* p, unsigned long long v) {
    __hip_atomic_store(p, v, __ATOMIC_RELAXED, __HIP_MEMORY_SCOPE_AGENT);
}
__device__ __forceinline__ void astf(float* p, float v) {
    __hip_atomic_store(p, v, __ATOMIC_RELAXED, __HIP_MEMORY_SCOPE_AGENT);
}
__device__ __forceinline__ void drain_vm() {
    asm volatile("s_waitcnt vmcnt(0)" ::: "memory");
}

typedef union { unsigned long long u[2]; f32x4 f; }  U128F;
typedef union { unsigned long long u; bf16x4 v; }    U64B;

// ---------------------------------------------------------------------------
// W [L][2048][4096] f32 -> Wt2 [L][128 slices][2 planes][65536] bf16.
// Slice s covers cols [s*32, s*32+32). Element ((nt*64+kcg)*64+lane)*8 + j
// = W[k][col] with col = s*32 + nt*16 + (lane&15), k = kcg*32 + (lane>>4)*8+j.
// kcg 0..31 = x-part (W rows 0..1023), 32..63 = h-part.
__global__ __launch_bounds__(256) void k_cvt_w2(const float* __restrict__ W,
                                                __bf16* __restrict__ Wt2) {
    const int s = blockIdx.x;
    const size_t l = blockIdx.y;
    const int tid = threadIdx.x;
    __bf16* dst = Wt2 + (l * GBLK + s) * SLICE_ELEMS;
    const float* Wl = W + l * 2048 * 4096;
    for (int i = tid; i < 8192; i += 256) {
        int ln = i & 63, kcg = (i >> 6) & 63, nt = i >> 12;
        int col = s * 32 + nt * 16 + (ln & 15);
        int k0 = kcg * 32 + (ln >> 4) * 8;
        const float* src = Wl + (size_t)k0 * 4096 + col;
        bf16x8 hi8, lo8;
#pragma unroll
        for (int j = 0; j < 8; ++j) {
            float x = src[(size_t)j * 4096];
            __bf16 h = (__bf16)x;
            hi8[j] = h; lo8[j] = (__bf16)(x - (float)h);
        }
        *(bf16x8*)(dst + i * 8) = hi8;
        *(bf16x8*)(dst + 65536 + i * 8) = lo8;
    }
}

// plain f32 -> bf16 (hi only), 8 elems/thread, exact grid
__global__ __launch_bounds__(256) void k_cvt(const float* __restrict__ in,
                                             __bf16* __restrict__ out) {
    size_t i = ((size_t)blockIdx.x * 256 + threadIdx.x) * 8;
    f32x4 v0 = *(const f32x4*)(in + i);
    f32x4 v1 = *(const f32x4*)(in + i + 4);
    bf16x8 o;
    o[0]=(__bf16)v0[0]; o[1]=(__bf16)v0[1]; o[2]=(__bf16)v0[2]; o[3]=(__bf16)v0[3];
    o[4]=(__bf16)v1[0]; o[5]=(__bf16)v1[1]; o[6]=(__bf16)v1[2]; o[7]=(__bf16)v1[3];
    *(bf16x8*)(out + i) = o;
}

// embedding gather -> time-major [t*32+b][1024] hi/lo bf16
__global__ __launch_bounds__(256) void k_embed(const int* __restrict__ idx,
                                               const float* __restrict__ emb,
                                               __bf16* __restrict__ xhi,
                                               __bf16* __restrict__ xlo) {
    const int row = blockIdx.x;            // t*32 + b
    const int t = row >> 5, b = row & 31;
    const int id = idx[b * SEQ + t];
    const int tid = threadIdx.x;
    f32x4 v = *(const f32x4*)(emb + (size_t)id * RNN + tid * 4);
    bf16x4 hi, lo;
#pragma unroll
    for (int j = 0; j < 4; ++j) {
        __bf16 h = (__bf16)v[j];
        hi[j] = h; lo[j] = (__bf16)(v[j] - (float)h);
    }
    *(bf16x4*)(xhi + (size_t)row * RNN + tid * 4) = hi;
    *(bf16x4*)(xlo + (size_t)row * RNN + tid * 4) = lo;
}

// ---------------------------------------------------------------------------
// Flat single-level fence-free barriers (round-11 proven form).
__device__ __forceinline__ void bar_all(unsigned* slots, int lb, int tid,
                                        unsigned gen, bool poll) {
    drain_vm();
    __syncthreads();
    if (tid == 0) ast(&slots[lb * AR_STRIDE], gen);
    if (poll && tid < GBLK) {
        while (ald(&slots[tid * AR_STRIDE]) < gen) __builtin_amdgcn_s_sleep(1);
    }
    __syncthreads();
}
__device__ __forceinline__ void bar_gate(unsigned* slots, int lb, bool arrive,
                                         int tid, unsigned gen) {
    drain_vm();
    __syncthreads();
    if (arrive && tid == 0) ast(&slots[lb * AR_STRIDE], gen);
    if (tid < BATCH) {
        while (ald(&slots[tid * AR_STRIDE]) < gen) __builtin_amdgcn_s_sleep(1);
    }
    __syncthreads();
}

// ---------------------------------------------------------------------------
// Pipelined layer-pair recurrence. 256 blocks: 0..127 layer A, 128..255
// layer B (one step behind; polls barA2 for x(B)[t]=h(A)[t]). Each block:
// 32 cols, full K=2048 (kh0 waves = x-part, kh1 = h-part), W-hi in LDS,
// W-lo streamed. Gates in blocks lb 0..31 of each half.
__global__ __launch_bounds__(256, 1) void k_pair(
        const __bf16* __restrict__ WtA, const __bf16* __restrict__ WtB,
        const float* __restrict__ biasA, const float* __restrict__ biasB,
        const float* __restrict__ gA, const float* __restrict__ bA,
        const float* __restrict__ gB, const float* __restrict__ bB,
        const __bf16* __restrict__ xah, const __bf16* __restrict__ xal, // A in
        __bf16* __restrict__ xmh, __bf16* __restrict__ xml,            // A out = B in
        __bf16* __restrict__ xoh2, __bf16* __restrict__ xol2,          // B out
        float* __restrict__ za, float* __restrict__ zb,
        unsigned* bar, unsigned gen0)
{
    __shared__ __bf16 wl[65536];          // 128 KB W-hi slice (lane-read order)
    __shared__ f32x4 pred[2][2][64];      // 4 KB partial accs [mt][nt][lane]
    __shared__ float red[4][8];

    const int bk = blockIdx.x, tid = threadIdx.x;
    const int lane = tid & 63, w = tid >> 6;
    const int q = lane & 15, g = lane >> 4;
    const int mt = w & 1, kh = w >> 1;
    const int zr0 = (mt << 4) + (g << 2);

    const bool isB = (bk >= GBLK);
    const int lb = bk & (GBLK - 1);
    const __bf16* WtS = (isB ? WtB : WtA) + (size_t)lb * SLICE_ELEMS;
    const __bf16* wlo = WtS + 65536;                 // streamed lo plane
    const float* bias = isB ? biasB : biasA;
    const float* g5 = isB ? gB : gA;
    const float* b5 = isB ? bB : bA;
    const __bf16* xih = isB ? (const __bf16*)xmh : xah;
    const __bf16* xil = isB ? (const __bf16*)xml : xal;
    __bf16* xoh = isB ? xoh2 : xmh;
    __bf16* xol = isB ? xol2 : xml;
    float* zbuf = isB ? zb : za;
    unsigned* b1 = bar + (isB ? 2 : 0) * GBLK * AR_STRIDE;
    unsigned* b2 = bar + (isB ? 3 : 1) * GBLK * AR_STRIDE;
    unsigned* xr = bar + 1 * GBLK * AR_STRIDE;       // barA2 (B's x-ready)
    const int ncol = lb * 32 + q;

    // ---- stage W-hi slice into LDS (linear copy, lane-read order) ----
    for (int i = tid; i < 8192; i += 256)
        *(bf16x8*)&wl[i * 8] = *(const bf16x8*)(WtS + i * 8);

    // ---- constants ----
    const bool is_gate = (lb < BATCH);
    float bv0 = 0.f, bv1 = 0.f;
    if (kh == 0) { bv0 = bias[ncol]; bv1 = bias[ncol + 16]; }
    f32x4 gi, bi, gj, bj, gf, bfv, go, bo, g4, b4;
    if (is_gate) {
        gi = *(const f32x4*)(g5 + 0*RNN + tid*4); bi = *(const f32x4*)(b5 + 0*RNN + tid*4);
        gj = *(const f32x4*)(g5 + 1*RNN + tid*4); bj = *(const f32x4*)(b5 + 1*RNN + tid*4);
        gf = *(const f32x4*)(g5 + 2*RNN + tid*4); bfv= *(const f32x4*)(b5 + 2*RNN + tid*4);
        go = *(const f32x4*)(g5 + 3*RNN + tid*4); bo = *(const f32x4*)(b5 + 3*RNN + tid*4);
        g4 = *(const f32x4*)(g5 + 4*RNN + tid*4); b4 = *(const f32x4*)(b5 + 4*RNN + tid*4);
    }
    const float inv = 1.f / (float)RNN;
    f32x4 creg = {0.f, 0.f, 0.f, 0.f};
    __syncthreads();   // LDS staged

    for (int t = 0; t < SEQ; ++t) {
        const unsigned gen = gen0 + (unsigned)t + 1u;
        // ---- B: wait until x(B)[t] = h(A)[t] is published ----
        if (isB) {
            if (tid < BATCH) {
                while (ald(&xr[tid * AR_STRIDE]) < gen) __builtin_amdgcn_s_sleep(1);
            }
            __syncthreads();
        }
        // ---- phase A: z[t] = [x[t]; h[t-1]] @ W  (kh0 = x, kh1 = h) ----
        f32x4 a00={0,0,0,0}, a01={0,0,0,0}, a02={0,0,0,0};
        f32x4 a10={0,0,0,0}, a11={0,0,0,0}, a12={0,0,0,0};
        const bool act = (kh == 0) || (t > 0);
        if (act) {
            const __bf16 *ah, *al;
            if (kh == 0) {
                ah = xih + ((size_t)t * BATCH + (mt << 4) + q) * RNN;
                al = xil + ((size_t)t * BATCH + (mt << 4) + q) * RNN;
            } else {
                ah = xoh + ((size_t)(t - 1) * BATCH + (mt << 4) + q) * RNN;
                al = xol + ((size_t)(t - 1) * BATCH + (mt << 4) + q) * RNN;
            }
#pragma unroll 4
            for (int kc = 0; kc < 32; ++kc) {
                const int kcg = (kh << 5) + kc;
                bf16x8 ahf = *(const bf16x8*)(ah + (kc << 5) + (g << 3));
                bf16x8 alf = *(const bf16x8*)(al + (kc << 5) + (g << 3));
                bf16x8 w0h = *(const bf16x8*)&wl[(kcg << 9) + (lane << 3)];
                bf16x8 w1h = *(const bf16x8*)&wl[((64 + kcg) << 9) + (lane << 3)];
                bf16x8 w0l = *(const bf16x8*)(wlo + (kcg << 9) + (lane << 3));
                bf16x8 w1l = *(const bf16x8*)(wlo + ((64 + kcg) << 9) + (lane << 3));
                a00 = __builtin_amdgcn_mfma_f32_16x16x32_bf16(ahf, w0h, a00, 0, 0, 0);
                a01 = __builtin_amdgcn_mfma_f32_16x16x32_bf16(alf, w0h, a01, 0, 0, 0);
                a02 = __builtin_amdgcn_mfma_f32_16x16x32_bf16(ahf, w0l, a02, 0, 0, 0);
                a10 = __builtin_amdgcn_mfma_f32_16x16x32_bf16(ahf, w1h, a10, 0, 0, 0);
                a11 = __builtin_amdgcn_mfma_f32_16x16x32_bf16(alf, w1h, a11, 0, 0, 0);
                a12 = __builtin_amdgcn_mfma_f32_16x16x32_bf16(ahf, w1l, a12, 0, 0, 0);
            }
        }
        {
            f32x4 s0, s1;
#pragma unroll
            for (int j = 0; j < 4; ++j) {
                s0[j] = a00[j] + a01[j] + a02[j];
                s1[j] = a10[j] + a11[j] + a12[j];
            }
            if (kh == 1) { pred[mt][0][lane] = s0; pred[mt][1][lane] = s1; }
            __syncthreads();
            if (kh == 0) {
                f32x4 p0 = pred[mt][0][lane], p1 = pred[mt][1][lane];
#pragma unroll
                for (int r = 0; r < 4; ++r) {
                    astf(&zbuf[(size_t)(zr0 + r) * 4096 + ncol],      s0[r] + p0[r] + bv0);
                    astf(&zbuf[(size_t)(zr0 + r) * 4096 + ncol + 16], s1[r] + p1[r] + bv1);
                }
            }
        }
        bar_all(b1, lb, tid, gen, is_gate);   // z visible (gates poll)

        // ---- phase B: gates (lb 0..31), c in registers ----
        if (is_gate) {
            const int b = lb;
            const float* zrow = zbuf + (size_t)b * 4096 + tid * 4;
            auto ld4 = [&](const float* p) -> f32x4 {
                U128F x;
                x.u[0] = ald64((const unsigned long long*)p);
                x.u[1] = ald64((const unsigned long long*)p + 1);
                return x.f;
            };
            f32x4 zi = ld4(zrow), zjv = ld4(zrow + 1024),
                  zfv = ld4(zrow + 2048), zov = ld4(zrow + 3072);
            float s[8];
            s[0] = zi[0]+zi[1]+zi[2]+zi[3];
            s[1] = zi[0]*zi[0]+zi[1]*zi[1]+zi[2]*zi[2]+zi[3]*zi[3];
            s[2] = zjv[0]+zjv[1]+zjv[2]+zjv[3];
            s[3] = zjv[0]*zjv[0]+zjv[1]*zjv[1]+zjv[2]*zjv[2]+zjv[3]*zjv[3];
            s[4] = zfv[0]+zfv[1]+zfv[2]+zfv[3];
            s[5] = zfv[0]*zfv[0]+zfv[1]*zfv[1]+zfv[2]*zfv[2]+zfv[3]*zfv[3];
            s[6] = zov[0]+zov[1]+zov[2]+zov[3];
            s[7] = zov[0]*zov[0]+zov[1]*zov[1]+zov[2]*zov[2]+zov[3]*zov[3];
#pragma unroll
            for (int o = 32; o; o >>= 1)
#pragma unroll
                for (int i = 0; i < 8; ++i) s[i] += __shfl_xor(s[i], o);
            if (lane == 0) {
#pragma unroll
                for (int i = 0; i < 8; ++i) red[w][i] = s[i];
            }
            __syncthreads();
            float tot[8];
#pragma unroll
            for (int i = 0; i < 8; ++i) tot[i] = red[0][i]+red[1][i]+red[2][i]+red[3][i];

            float mi = tot[0]*inv, ri = rsqrtf(tot[1]*inv - mi*mi + 1e-5f);
            float mj = tot[2]*inv, rj = rsqrtf(tot[3]*inv - mj*mj + 1e-5f);
            float mf = tot[4]*inv, rf = rsqrtf(tot[5]*inv - mf*mf + 1e-5f);
            float mo = tot[6]*inv, ro = rsqrtf(tot[7]*inv - mo*mo + 1e-5f);

            f32x4 onrm;
            float cs = 0.f, cq = 0.f;
#pragma unroll
            for (int j = 0; j < 4; ++j) {
                float iv = (zi[j]-mi)*ri*gi[j] + bi[j];
                float jv = (zjv[j]-mj)*rj*gj[j] + bj[j];
                float fv = (zfv[j]-mf)*rf*gf[j] + bfv[j];
                float ov = (zov[j]-mo)*ro*go[j] + bo[j];
                float cc = creg[j] * sigm(fv + 1.0f) + sigm(iv) * tanhf(jv);
                creg[j] = cc; onrm[j] = ov;
                cs += cc; cq += cc*cc;
            }

            __syncthreads();   // protect red[] reuse
            float s2a = cs, s2b = cq;
#pragma unroll
            for (int o = 32; o; o >>= 1) { s2a += __shfl_xor(s2a, o); s2b += __shfl_xor(s2b, o); }
            if (lane == 0) { red[w][0] = s2a; red[w][1] = s2b; }
            __syncthreads();
            float mc = (red[0][0]+red[1][0]+red[2][0]+red[3][0]) * inv;
            float vc = (red[0][1]+red[1][1]+red[2][1]+red[3][1]) * inv - mc*mc;
            float rc = rsqrtf(vc + 1e-5f);

            bf16x4 hh, hl;
#pragma unroll
            for (int j = 0; j < 4; ++j) {
                float cn = (creg[j]-mc)*rc*g4[j] + b4[j];
                float h = tanhf(cn) * sigm(onrm[j]);
                __bf16 a = (__bf16)h;
                hh[j] = a; hl[j] = (__bf16)(h - (float)a);
            }
            U64B ph, pl;
            ph.v = hh; pl.v = hl;
            ast64((unsigned long long*)&xoh[((size_t)t * BATCH + b) * RNN + tid * 4], ph.u);
            ast64((unsigned long long*)&xol[((size_t)t * BATCH + b) * RNN + tid * 4], pl.u);
        }
        bar_gate(b2, lb, is_gate, tid, gen);   // h visible
    }
}

// ---------------------------------------------------------------------------
// k_proj (round-10 proven): logits[m][v] = sum_k h[m][k]*smw[v][k] + smb[v].
// 128x128 tile, BK=32, double-buffered reg-staging, XCD-chunked m-fastest.
__global__ __launch_bounds__(256) void k_proj(const __bf16* __restrict__ xs,
                                              const __bf16* __restrict__ wv,
                                              const float* __restrict__ sb,
                                              float* __restrict__ out) {
    __shared__ __bf16 Asm[2][8][512];
    __shared__ __bf16 Bsm[2][8][512];
    const int tid = threadIdx.x;
    const int lane = tid & 63, w = tid >> 6;
    const int wm = w & 1, wn = w >> 1;
    const int bid = blockIdx.x;            // 8000 blocks (250 n x 32 m)
    const int swz = (bid & 7) * 1000 + (bid >> 3);
    const int m0 = (swz & 31) << 7;
    const int n0 = (swz >> 5) << 7;
    const int mb = m0 >> 7;

    const int lr = lane >> 2, cc4 = lane & 3;
    const __bf16* asrc[2];
    const __bf16* bsrc[2];
#pragma unroll
    for (int p = 0; p < 2; ++p) {
        int st = p * 4 + w;
        asrc[p] = xs + (size_t)((st * 16 + lr) * 32 + mb) * RNN + cc4 * 8;
        bsrc[p] = wv + (size_t)(n0 + st * 16 + lr) * RNN + cc4 * 8;
    }
    const int gidx = cc4 * 16 + lr;

    f32x4 acc[4][4];
#pragma unroll
    for (int i = 0; i < 4; ++i)
#pragma unroll
        for (int j = 0; j < 4; ++j) acc[i][j] = (f32x4){0.f, 0.f, 0.f, 0.f};

    bf16x8 ar[2], br[2];
#pragma unroll
    for (int p = 0; p < 2; ++p) {
        ar[p] = *(const bf16x8*)(asrc[p]);
        br[p] = *(const bf16x8*)(bsrc[p]);
    }
#pragma unroll
    for (int p = 0; p < 2; ++p) {
        int st = p * 4 + w;
        *(bf16x8*)&Asm[0][st][gidx * 8] = ar[p];
        *(bf16x8*)&Bsm[0][st][gidx * 8] = br[p];
    }
    __syncthreads();

    for (int s = 0; s < 32; ++s) {
        const int buf = s & 1;
        if (s + 1 < 32) {
            const int k0 = (s + 1) * 32;
#pragma unroll
            for (int p = 0; p < 2; ++p) {
                ar[p] = *(const bf16x8*)(asrc[p] + k0);
                br[p] = *(const bf16x8*)(bsrc[p] + k0);
            }
        }
        bf16x8 af[4], bfr[4];
#pragma unroll
        for (int i = 0; i < 4; ++i) {
            af[i]  = *(const bf16x8*)&Asm[buf][wm * 4 + i][lane * 8];
            bfr[i] = *(const bf16x8*)&Bsm[buf][wn * 4 + i][lane * 8];
        }
#pragma unroll
        for (int mi = 0; mi < 4; ++mi)
#pragma unroll
            for (int ni = 0; ni < 4; ++ni)
                acc[mi][ni] = __builtin_amdgcn_mfma_f32_16x16x32_bf16(
                    af[mi], bfr[ni], acc[mi][ni], 0, 0, 0);
        if (s + 1 < 32) {
#pragma unroll
            for (int p = 0; p < 2; ++p) {
                int st = p * 4 + w;
                *(bf16x8*)&Asm[buf ^ 1][st][gidx * 8] = ar[p];
                *(bf16x8*)&Bsm[buf ^ 1][st][gidx * 8] = br[p];
            }
        }
        __syncthreads();
    }

    const int q = lane & 15, g = lane >> 4;
#pragma unroll
    for (int ni = 0; ni < 4; ++ni) {
        const int n = n0 + wn * 64 + ni * 16 + q;
        const float bv = sb[n];
#pragma unroll
        for (int mi = 0; mi < 4; ++mi) {
            const int mbase = m0 + wm * 64 + mi * 16 + g * 4;
#pragma unroll
            for (int r = 0; r < 4; ++r)
                __builtin_nontemporal_store(acc[mi][ni][r] + bv,
                                            &out[(size_t)(mbase + r) * VOCAB + n]);
        }
    }
}

// ---------------------------------------------------------------------------
extern "C" void kernel_launch(void* const* d_in, const int* in_sizes, int n_in,
                              void* d_out, int out_size, void* d_ws, size_t ws_size,
                              hipStream_t stream) {
    const int*   input = (const int*)  d_in[0];
    const float* emb   = (const float*)d_in[1];
    const float* W     = (const float*)d_in[2];
    const float* bias  = (const float*)d_in[3];
    const float* ln_g  = (const float*)d_in[4];
    const float* ln_b  = (const float*)d_in[5];
    const float* smw   = (const float*)d_in[6];
    const float* smb   = (const float*)d_in[7];
    float* out = (float*)d_out;

    char* p = (char*)d_ws;
    auto alloc = [&](size_t bytes) { char* r = p; p += (bytes + 255) & ~(size_t)255; return r; };
    __bf16* Wt2  = (__bf16*)alloc((size_t)NLAY * LAYER_ELEMS * 2);     // 128 MiB
    __bf16* smwb = (__bf16*)alloc((size_t)VOCAB * RNN * 2);            // 65.5 MB
    const size_t XB = (size_t)SEQ * BATCH * RNN * 2;                   // 8.4 MB
    __bf16* x0h = (__bf16*)alloc(XB); __bf16* x0l = (__bf16*)alloc(XB);
    __bf16* x1h = (__bf16*)alloc(XB); __bf16* x1l = (__bf16*)alloc(XB);
    __bf16* x2h = (__bf16*)alloc(XB); __bf16* x2l = (__bf16*)alloc(XB);
    __bf16* x3h = (__bf16*)alloc(XB); __bf16* x3l = (__bf16*)alloc(XB);
    __bf16* x4h = (__bf16*)alloc(XB); __bf16* x4l = (__bf16*)alloc(XB);
    float*  za  = (float*) alloc((size_t)BATCH * 4096 * 4);            // 512 KB
    float*  zb  = (float*) alloc((size_t)BATCH * 4096 * 4);            // 512 KB
    unsigned* bar= (unsigned*)alloc(4 * GBLK * AR_STRIDE * 4);         // 4 slot arrays

    hipMemsetAsync(bar, 0, 4 * GBLK * AR_STRIDE * 4, stream);

    k_cvt_w2<<<dim3(GBLK, NLAY), 256, 0, stream>>>(W, Wt2);
    k_cvt<<<(VOCAB * RNN) / (8 * 256), 256, 0, stream>>>(smw, smwb);
    k_embed<<<SEQ * BATCH, 256, 0, stream>>>(input, emb, x0h, x0l);

    for (int pr = 0; pr < 2; ++pr) {
        const __bf16* WtA_ = Wt2 + (size_t)(2 * pr)     * LAYER_ELEMS;
        const __bf16* WtB_ = Wt2 + (size_t)(2 * pr + 1) * LAYER_ELEMS;
        const float* bA_ = bias + (size_t)(2 * pr)     * 4096;
        const float* bB_ = bias + (size_t)(2 * pr + 1) * 4096;
        const float* gA_ = ln_g + (size_t)(2 * pr)     * 5 * RNN;
        const float* bgA_= ln_b + (size_t)(2 * pr)     * 5 * RNN;
        const float* gB_ = ln_g + (size_t)(2 * pr + 1) * 5 * RNN;
        const float* bgB_= ln_b + (size_t)(2 * pr + 1) * 5 * RNN;
        const __bf16* xah_ = pr ? x2h : x0h;
        const __bf16* xal_ = pr ? x2l : x0l;
        __bf16* xmh_ = pr ? x3h : x1h;
        __bf16* xml_ = pr ? x3l : x1l;
        __bf16* xoh_ = pr ? x4h : x2h;
        __bf16* xol_ = pr ? x4l : x2l;
        float *za_ = za, *zb_ = zb;
        unsigned* bar_ = bar;
        unsigned gen0 = (unsigned)(pr * SEQ);
        void* args[] = {(void*)&WtA_, (void*)&WtB_, (void*)&bA_, (void*)&bB_,
                        (void*)&gA_, (void*)&bgA_, (void*)&gB_, (void*)&bgB_,
                        (void*)&xah_, (void*)&xal_, (void*)&xmh_, (void*)&xml_,
                        (void*)&xoh_, (void*)&xol_, (void*)&za_, (void*)&zb_,
                        (void*)&bar_, (void*)&gen0};
        hipLaunchCooperativeKernel((const void*)k_pair,
                                   dim3(2 * GBLK), dim3(256), args, 0, stream);
    }
    // final layer output (bf16 hi) lives in x4h (time-major)
    k_proj<<<dim3(8000), 256, 0, stream>>>(x4h, smwb, smb, out);
}